// Round 5
// baseline (94.372 us; speedup 1.0000x reference)
//
#include <hip/hip_runtime.h>
#include <hip/hip_fp8.h>

// GE2E loss, fp8-MFMA v3: 64 rows/block. input [N=1024][M=20][D=256] fp32.
//   prep (256 blocks, 4 speakers/block, 1 wave each): centroid c (fp32 c_raw),
//     cc=||c||^2, c_hat -> fp8 e4m3 pre-swizzled in 32x32x16 fp8 B-frag order.
//     Zeroes out.
//   main (320 blocks, 4 waves, (256,2) -> ALL blocks resident in one round):
//     64 rows x 1024 cols per block. Staging: float4 loads, exact fp32
//     uu/uc; s=w*rsqrt(uu) folded into A before fp8 quantization -> MFMA
//     output IS the scaled similarity (b cancels). Per wave: 8 col-tiles of
//     32; per tile 8 dwordx4 B loads feed 32 MFMAs (4 indep 8-chains, two
//     32-row A-halves reuse each B) -> 2x arithmetic intensity per B byte vs
//     v2; exp-VALU of one wave overlaps MFMA of the co-resident wave.
//     t-loop rolled (unroll 1) to bound VGPR (~215, no spill at cap 256).
//     Armor: exp clamped, rsqrt/log floored -> NaN structurally impossible.
//     Self-col swap from exact fp32 scalars. One atomicAdd per block.

#define D_DIM 256
#define N_SPK 1024
#define M_UTT 20
#define ROWS  64

typedef long lx2 __attribute__((ext_vector_type(2)));
typedef float f32x16 __attribute__((ext_vector_type(16)));

__device__ __forceinline__ int pk4_fp8(float x0, float x1, float x2, float x3) {
#if __has_builtin(__builtin_amdgcn_cvt_pk_fp8_f32)
  int v = __builtin_amdgcn_cvt_pk_fp8_f32(x0, x1, 0, false);
  v = __builtin_amdgcn_cvt_pk_fp8_f32(x2, x3, v, true);
  return v;
#else
  union { int i; unsigned char b[4]; } u;
  u.b[0] = __hip_fp8_e4m3(x0).__x;
  u.b[1] = __hip_fp8_e4m3(x1).__x;
  u.b[2] = __hip_fp8_e4m3(x2).__x;
  u.b[3] = __hip_fp8_e4m3(x3).__x;
  return u.i;
#endif
}

// ---------------- Kernel A: centroid prep (1 wave per speaker) ----------------
__global__ __launch_bounds__(256) void ge2e_prep(
    const float* __restrict__ inp, unsigned int* __restrict__ bsw32,
    float* __restrict__ c_raw, float* __restrict__ ccv,
    float* __restrict__ out) {
  const int tid = threadIdx.x, lane = tid & 63, wv = tid >> 6;
  const int s = blockIdx.x * 4 + wv;  // speaker; lane owns dims 4*lane..+3
  if (blockIdx.x == 0 && tid == 0) out[0] = 0.0f;

  const float4* up =
      reinterpret_cast<const float4*>(inp + (size_t)s * (M_UTT * D_DIM)) + lane;
  float4 a = make_float4(0.f, 0.f, 0.f, 0.f);
#pragma unroll
  for (int m = 0; m < M_UTT; ++m) {
    const float4 f = up[m * (D_DIM / 4)];
    a.x += f.x; a.y += f.y; a.z += f.z; a.w += f.w;
  }
  const float inv = 1.0f / (float)M_UTT;
  const float4 c = make_float4(a.x * inv, a.y * inv, a.z * inv, a.w * inv);
  reinterpret_cast<float4*>(c_raw + (size_t)s * D_DIM)[lane] = c;

  float cc = c.x * c.x + c.y * c.y + c.z * c.z + c.w * c.w;
#pragma unroll
  for (int o = 1; o < 64; o <<= 1) cc += __shfl_xor(cc, o, 64);
  if (lane == 0) ccv[s] = cc;

  const float r = rsqrtf(fmaxf(cc, 1e-20f));
  const int q = pk4_fp8(c.x * r, c.y * r, c.z * r, c.w * r);
  // B-frag: lane l holds B[n=l&31][k=(l>>5)*8+j]; mem [tile*8+p][64][16B].
  // d = 4*lane: p=lane>>3, sub=(lane>>2)&1, half=(lane>>1)&1, j0=(lane&1)*4.
  const int t = s >> 5, n5 = s & 31;
  const int p = lane >> 3, sub = (lane >> 2) & 1;
  const int half = (lane >> 1) & 1, jb = (lane & 1) * 4;
  bsw32[((((t * 8 + p) * 64) + half * 32 + n5) * 16 + sub * 8 + jb) >> 2] =
      (unsigned int)q;
}

// ---------------- Kernel B: fp8 MFMA GEMM + fused sumexp ----------------
__global__ __launch_bounds__(256, 2) void ge2e_main(
    const float* __restrict__ inp, const float* __restrict__ wp,
    const unsigned char* __restrict__ bsw, const float* __restrict__ c_raw,
    const float* __restrict__ ccv, float* __restrict__ out) {
  __shared__ __align__(16) unsigned char lA[ROWS * D_DIM];  // 16 KB A-frags
  __shared__ float uuL[ROWS], ucL[ROWS], ccL[ROWS];
  __shared__ float rowtot[4][ROWS];
  const int tid = threadIdx.x;
  const int r0 = blockIdx.x * ROWS;
  const float w = wp[0];

  // ---- staging: 4 threads/row (64 dims each); fold s=w/||u|| into A ----
  {
    const int m = tid >> 2, seg = tid & 3;
    const int r = r0 + m, nr = r / M_UTT;
    const float4* urow =
        reinterpret_cast<const float4*>(inp + (size_t)r * D_DIM + seg * 64);
    const float4* crow =
        reinterpret_cast<const float4*>(c_raw + (size_t)nr * D_DIM + seg * 64);
    float4 uf[16];
    float uu = 0.f, uc = 0.f;
#pragma unroll
    for (int q = 0; q < 16; ++q) {
      uf[q] = urow[q];
      const float4 cf = crow[q];
      uu += uf[q].x * uf[q].x + uf[q].y * uf[q].y + uf[q].z * uf[q].z +
            uf[q].w * uf[q].w;
      uc += uf[q].x * cf.x + uf[q].y * cf.y + uf[q].z * cf.z + uf[q].w * cf.w;
    }
#pragma unroll
    for (int o = 1; o < 4; o <<= 1) {
      uu += __shfl_xor(uu, o, 64);
      uc += __shfl_xor(uc, o, 64);
    }
    const float s = w * rsqrtf(fmaxf(uu, 1e-20f));
    // A-frag mem: int4 slot [H(m>>5)*512 + p*64 + half*32 + (m&31)],
    // p covers k in [32p,32p+32): ch0 -> half0 {k0-7,k16-23}, ch1 -> half1.
    const int H = m >> 5, m31 = m & 31;
    int4* dst = reinterpret_cast<int4*>(lA) + H * 512 + m31;
#pragma unroll
    for (int pp = 0; pp < 2; ++pp) {
      const int p = 2 * seg + pp;
      const float4* f = uf + pp * 8;
      int4 ch0, ch1;
      ch0.x = pk4_fp8(s * f[0].x, s * f[0].y, s * f[0].z, s * f[0].w);
      ch0.y = pk4_fp8(s * f[1].x, s * f[1].y, s * f[1].z, s * f[1].w);
      ch0.z = pk4_fp8(s * f[4].x, s * f[4].y, s * f[4].z, s * f[4].w);
      ch0.w = pk4_fp8(s * f[5].x, s * f[5].y, s * f[5].z, s * f[5].w);
      ch1.x = pk4_fp8(s * f[2].x, s * f[2].y, s * f[2].z, s * f[2].w);
      ch1.y = pk4_fp8(s * f[3].x, s * f[3].y, s * f[3].z, s * f[3].w);
      ch1.z = pk4_fp8(s * f[6].x, s * f[6].y, s * f[6].z, s * f[6].w);
      ch1.w = pk4_fp8(s * f[7].x, s * f[7].y, s * f[7].z, s * f[7].w);
      dst[p * 64] = ch0;
      dst[p * 64 + 32] = ch1;
    }
    if (seg == 0) {
      uuL[m] = uu;
      ucL[m] = uc;
      ccL[m] = ccv[nr];
    }
  }
  __syncthreads();

  const int lane = tid & 63, wv = tid >> 6, hl = lane >> 5;
  const lx2* lAv = reinterpret_cast<const lx2*>(lA);
  lx2 A0[8], A1[8];
#pragma unroll
  for (int p = 0; p < 8; ++p) {
    A0[p] = lAv[p * 64 + lane];        // rows 0..31
    A1[p] = lAv[512 + p * 64 + lane];  // rows 32..63
  }

  float sume0[16], sume1[16];
#pragma unroll
  for (int i = 0; i < 16; ++i) { sume0[i] = 0.0f; sume1[i] = 0.0f; }

  const lx2* Bv = reinterpret_cast<const lx2*>(bsw);
#pragma unroll 1
  for (int t = 0; t < 8; ++t) {
    const lx2* Bt = Bv + (size_t)(wv * 8 + t) * 512 + lane;
    lx2 B[8];
#pragma unroll
    for (int p = 0; p < 8; ++p) B[p] = Bt[p * 64];
    f32x16 a00, a01, a10, a11;
#pragma unroll
    for (int i = 0; i < 16; ++i) {
      a00[i] = 0.0f; a01[i] = 0.0f; a10[i] = 0.0f; a11[i] = 0.0f;
    }
#pragma unroll
    for (int p = 0; p < 8; ++p) {
      a00 = __builtin_amdgcn_mfma_f32_32x32x16_fp8_fp8(A0[p].x, B[p].x, a00,
                                                       0, 0, 0);
      a01 = __builtin_amdgcn_mfma_f32_32x32x16_fp8_fp8(A0[p].y, B[p].y, a01,
                                                       0, 0, 0);
      a10 = __builtin_amdgcn_mfma_f32_32x32x16_fp8_fp8(A1[p].x, B[p].x, a10,
                                                       0, 0, 0);
      a11 = __builtin_amdgcn_mfma_f32_32x32x16_fp8_fp8(A1[p].y, B[p].y, a11,
                                                       0, 0, 0);
    }
#pragma unroll
    for (int i = 0; i < 16; ++i) {
      sume0[i] += __expf(fminf(a00[i] + a01[i], 40.0f));  // armor: no inf
      sume1[i] += __expf(fminf(a10[i] + a11[i], 40.0f));
    }
  }

  // ---- reduce sumexp over the wave's 256 cols ----
#pragma unroll
  for (int i = 0; i < 16; ++i) {
    float v0 = sume0[i], v1 = sume1[i];
#pragma unroll
    for (int o = 1; o < 32; o <<= 1) {
      v0 += __shfl_xor(v0, o, 64);
      v1 += __shfl_xor(v1, o, 64);
    }
    sume0[i] = v0; sume1[i] = v1;
  }
  if ((lane & 31) == 0) {
#pragma unroll
    for (int i = 0; i < 16; ++i) {
      const int idx = (i & 3) + 8 * (i >> 2) + 4 * hl;
      rowtot[wv][idx] = sume0[i];
      rowtot[wv][32 + idx] = sume1[i];
    }
  }
  __syncthreads();

  // ---- per-row epilogue: self-column swap (exact fp32) + log ----
  if (tid < ROWS) {
    const float se0 = rowtot[0][tid] + rowtot[1][tid] + rowtot[2][tid] +
                      rowtot[3][tid];
    const float uu = uuL[tid], uc = ucL[tid], cc = ccL[tid];
    const float Mf = (float)M_UTT;
    const float ue = (Mf * uc - uu) * (1.0f / (Mf - 1.0f));
    const float ee = (Mf * Mf * cc - 2.0f * Mf * uc + uu) *
                     (1.0f / ((Mf - 1.0f) * (Mf - 1.0f)));
    const float sself = w * ue * rsqrtf(fmaxf(uu * ee, 1e-20f));
    const float sown = w * uc * rsqrtf(fmaxf(uu * cc, 1e-20f));
    const float se = fmaxf(
        se0 + __expf(fminf(sself, 40.f)) - __expf(fminf(sown, 40.f)), 1e-10f);
    float v = __logf(se) - sself;  // LSE - target logit (b cancels)
#pragma unroll
    for (int o = 1; o < 64; o <<= 1) v += __shfl_xor(v, o, 64);
    if (tid == 0) atomicAdd(out, v);
  }
}

extern "C" void kernel_launch(void* const* d_in, const int* in_sizes, int n_in,
                              void* d_out, int out_size, void* d_ws, size_t ws_size,
                              hipStream_t stream) {
  const float* inp = (const float*)d_in[0];
  const float* wp  = (const float*)d_in[1];
  // d_in[2] (b) cancels in LSE - sim_self.
  float* out = (float*)d_out;

  unsigned char* bsw = (unsigned char*)d_ws;            // 256 KB fp8 B-frags
  float* c_raw = (float*)((char*)d_ws + 256 * 1024);    // 1 MB
  float* ccv   = c_raw + (size_t)N_SPK * D_DIM;         // 4 KB

  ge2e_prep<<<N_SPK / 4, 256, 0, stream>>>(inp, (unsigned int*)bsw, c_raw, ccv,
                                           out);
  ge2e_main<<<(N_SPK * M_UTT) / ROWS, 256, 0, stream>>>(inp, wp, bsw, c_raw,
                                                        ccv, out);
}

// Round 6
// 89.797 us; speedup vs baseline: 1.0509x; 1.0509x over previous
//
#include <hip/hip_runtime.h>
#include <hip/hip_fp8.h>

// GE2E loss, fp8-MFMA v4. input [N=1024][M=20][D=256] fp32 -> scalar.
//   prep (256 blocks, 4 speakers/block, 1 wave each): centroid c (fp32 c_raw),
//     cc=||c||^2, c_hat -> fp8 e4m3 pre-swizzled in 32x32x16 fp8 B-frag order.
//     Zeroes out.
//   main (640 blocks, 4 waves, natural VGPR ~140 -> 3 waves/SIMD -> all 640
//     resident in one scheduling round): 32 rows x 1024 cols. Staging: float4
//     loads, exact fp32 uu/uc; s=w*rsqrt(uu) folded into A before fp8
//     quantization -> MFMA output IS the scaled similarity (b cancels).
//     Per wave: 8 col-tiles of 32; 8 dwordx4 B loads + 16 MFMAs (2 indep
//     8-chains) + 16 exp-acc per tile. No register-rotate pipeline (the
//     copies forced vmcnt drains; TLP at 12 waves/CU hides latency instead).
//     Armor: exp clamped, rsqrt/log floored -> NaN structurally impossible.
//     Self-col swap from exact fp32 scalars. One atomicAdd per block.

#define D_DIM 256
#define N_SPK 1024
#define M_UTT 20

typedef long lx2 __attribute__((ext_vector_type(2)));
typedef float f32x16 __attribute__((ext_vector_type(16)));

__device__ __forceinline__ int pk4_fp8(float x0, float x1, float x2, float x3) {
#if __has_builtin(__builtin_amdgcn_cvt_pk_fp8_f32)
  int v = __builtin_amdgcn_cvt_pk_fp8_f32(x0, x1, 0, false);
  v = __builtin_amdgcn_cvt_pk_fp8_f32(x2, x3, v, true);
  return v;
#else
  union { int i; unsigned char b[4]; } u;
  u.b[0] = __hip_fp8_e4m3(x0).__x;
  u.b[1] = __hip_fp8_e4m3(x1).__x;
  u.b[2] = __hip_fp8_e4m3(x2).__x;
  u.b[3] = __hip_fp8_e4m3(x3).__x;
  return u.i;
#endif
}

// ---------------- Kernel A: centroid prep (1 wave per speaker) ----------------
__global__ __launch_bounds__(256) void ge2e_prep(
    const float* __restrict__ inp, unsigned int* __restrict__ bsw32,
    float* __restrict__ c_raw, float* __restrict__ ccv,
    float* __restrict__ out) {
  const int tid = threadIdx.x, lane = tid & 63, wv = tid >> 6;
  const int s = blockIdx.x * 4 + wv;  // speaker; lane owns dims 4*lane..+3
  if (blockIdx.x == 0 && tid == 0) out[0] = 0.0f;

  const float4* up =
      reinterpret_cast<const float4*>(inp + (size_t)s * (M_UTT * D_DIM)) + lane;
  float4 a = make_float4(0.f, 0.f, 0.f, 0.f);
#pragma unroll
  for (int m = 0; m < M_UTT; ++m) {
    const float4 f = up[m * (D_DIM / 4)];
    a.x += f.x; a.y += f.y; a.z += f.z; a.w += f.w;
  }
  const float inv = 1.0f / (float)M_UTT;
  const float4 c = make_float4(a.x * inv, a.y * inv, a.z * inv, a.w * inv);
  reinterpret_cast<float4*>(c_raw + (size_t)s * D_DIM)[lane] = c;

  float cc = c.x * c.x + c.y * c.y + c.z * c.z + c.w * c.w;
#pragma unroll
  for (int o = 1; o < 64; o <<= 1) cc += __shfl_xor(cc, o, 64);
  if (lane == 0) ccv[s] = cc;

  const float r = rsqrtf(fmaxf(cc, 1e-20f));
  const int q = pk4_fp8(c.x * r, c.y * r, c.z * r, c.w * r);
  // B-frag: lane l holds B[n=l&31][k=(l>>5)*8+j]; mem [tile*8+p][64][16B].
  // d = 4*lane: p=lane>>3, sub=(lane>>2)&1, half=(lane>>1)&1, j0=(lane&1)*4.
  const int t = s >> 5, n5 = s & 31;
  const int p = lane >> 3, sub = (lane >> 2) & 1;
  const int half = (lane >> 1) & 1, jb = (lane & 1) * 4;
  bsw32[((((t * 8 + p) * 64) + half * 32 + n5) * 16 + sub * 8 + jb) >> 2] =
      (unsigned int)q;
}

// ---------------- Kernel B: fp8 MFMA GEMM + fused sumexp ----------------
__global__ __launch_bounds__(256) void ge2e_main(
    const float* __restrict__ inp, const float* __restrict__ wp,
    const unsigned char* __restrict__ bsw, const float* __restrict__ c_raw,
    const float* __restrict__ ccv, float* __restrict__ out) {
  __shared__ __align__(16) unsigned char lA[32 * D_DIM];  // 8 KB, A-frag order
  __shared__ float uuL[32], ucL[32], ccL[32];
  __shared__ float rowtot[4][32];
  const int tid = threadIdx.x;
  const int r0 = blockIdx.x * 32;
  const float w = wp[0];

  // ---- staging: 8 threads per row; fold s=w/||u|| into fp8 A-frags ----
  {
    const int m = tid >> 3, seg = tid & 7;
    const int r = r0 + m, nr = r / M_UTT;
    const float4* urow =
        reinterpret_cast<const float4*>(inp + (size_t)r * D_DIM + seg * 32);
    const float4* crow =
        reinterpret_cast<const float4*>(c_raw + (size_t)nr * D_DIM + seg * 32);
    float4 uf[8];
    float uu = 0.f, uc = 0.f;
#pragma unroll
    for (int q = 0; q < 8; ++q) {
      uf[q] = urow[q];
      const float4 cf = crow[q];
      uu += uf[q].x * uf[q].x + uf[q].y * uf[q].y + uf[q].z * uf[q].z +
            uf[q].w * uf[q].w;
      uc += uf[q].x * cf.x + uf[q].y * cf.y + uf[q].z * cf.z + uf[q].w * cf.w;
    }
#pragma unroll
    for (int o = 1; o < 8; o <<= 1) {
      uu += __shfl_xor(uu, o, 64);
      uc += __shfl_xor(uc, o, 64);
    }
    const float s = w * rsqrtf(fmaxf(uu, 1e-20f));
    // A-frag: lane l holds A[m=l&31][k=(l>>5)*8+j]; mem [kspair][lane][sub*8+j]
    int4 ch0, ch1;
    ch0.x = pk4_fp8(s * uf[0].x, s * uf[0].y, s * uf[0].z, s * uf[0].w); // k0-3
    ch0.y = pk4_fp8(s * uf[1].x, s * uf[1].y, s * uf[1].z, s * uf[1].w); // k4-7
    ch0.z = pk4_fp8(s * uf[4].x, s * uf[4].y, s * uf[4].z, s * uf[4].w); // k16-19
    ch0.w = pk4_fp8(s * uf[5].x, s * uf[5].y, s * uf[5].z, s * uf[5].w); // k20-23
    ch1.x = pk4_fp8(s * uf[2].x, s * uf[2].y, s * uf[2].z, s * uf[2].w); // k8-11
    ch1.y = pk4_fp8(s * uf[3].x, s * uf[3].y, s * uf[3].z, s * uf[3].w); // k12-15
    ch1.z = pk4_fp8(s * uf[6].x, s * uf[6].y, s * uf[6].z, s * uf[6].w); // k24-27
    ch1.w = pk4_fp8(s * uf[7].x, s * uf[7].y, s * uf[7].z, s * uf[7].w); // k28-31
    reinterpret_cast<int4*>(lA)[seg * 64 + m] = ch0;       // half 0 (lanes <32)
    reinterpret_cast<int4*>(lA)[seg * 64 + m + 32] = ch1;  // half 1 (lanes >=32)
    if (seg == 0) {
      uuL[m] = uu;
      ucL[m] = uc;
      ccL[m] = ccv[nr];
    }
  }
  __syncthreads();

  const int lane = tid & 63, wv = tid >> 6, hl = lane >> 5;
  lx2 A[8];
  const lx2* lAv = reinterpret_cast<const lx2*>(lA);
#pragma unroll
  for (int p = 0; p < 8; ++p) A[p] = lAv[p * 64 + lane];

  float sume[16];
#pragma unroll
  for (int i = 0; i < 16; ++i) sume[i] = 0.0f;

  const lx2* Bv = reinterpret_cast<const lx2*>(bsw);
#pragma unroll 1
  for (int t = 0; t < 8; ++t) {
    const lx2* Bt = Bv + (size_t)(wv * 8 + t) * 512 + lane;
    lx2 B[8];
#pragma unroll
    for (int p = 0; p < 8; ++p) B[p] = Bt[p * 64];
    f32x16 acc0, acc1;
#pragma unroll
    for (int i = 0; i < 16; ++i) { acc0[i] = 0.0f; acc1[i] = 0.0f; }
#pragma unroll
    for (int p = 0; p < 8; ++p) {
      acc0 = __builtin_amdgcn_mfma_f32_32x32x16_fp8_fp8(A[p].x, B[p].x, acc0,
                                                        0, 0, 0);
      acc1 = __builtin_amdgcn_mfma_f32_32x32x16_fp8_fp8(A[p].y, B[p].y, acc1,
                                                        0, 0, 0);
    }
#pragma unroll
    for (int i = 0; i < 16; ++i)
      sume[i] += __expf(fminf(acc0[i] + acc1[i], 40.0f));  // armor: no inf
  }

  // ---- reduce sumexp over the wave's 256 cols ----
#pragma unroll
  for (int i = 0; i < 16; ++i) {
    float v = sume[i];
#pragma unroll
    for (int o = 1; o < 32; o <<= 1) v += __shfl_xor(v, o, 64);
    sume[i] = v;
  }
  if ((lane & 31) == 0) {
#pragma unroll
    for (int i = 0; i < 16; ++i)
      rowtot[wv][(i & 3) + 8 * (i >> 2) + 4 * hl] = sume[i];
  }
  __syncthreads();

  // ---- per-row epilogue: self-column swap (exact fp32) + log ----
  if (tid < 32) {
    const float se0 = rowtot[0][tid] + rowtot[1][tid] + rowtot[2][tid] +
                      rowtot[3][tid];
    const float uu = uuL[tid], uc = ucL[tid], cc = ccL[tid];
    const float Mf = (float)M_UTT;
    const float ue = (Mf * uc - uu) * (1.0f / (Mf - 1.0f));
    const float ee = (Mf * Mf * cc - 2.0f * Mf * uc + uu) *
                     (1.0f / ((Mf - 1.0f) * (Mf - 1.0f)));
    const float sself = w * ue * rsqrtf(fmaxf(uu * ee, 1e-20f));
    const float sown = w * uc * rsqrtf(fmaxf(uu * cc, 1e-20f));
    const float se = fmaxf(
        se0 + __expf(fminf(sself, 40.f)) - __expf(fminf(sown, 40.f)), 1e-10f);
    float v = __logf(se) - sself;  // LSE - target logit (b cancels)
#pragma unroll
    for (int o = 1; o < 32; o <<= 1) v += __shfl_xor(v, o, 64);
    if (tid == 0) atomicAdd(out, v);
  }
}

extern "C" void kernel_launch(void* const* d_in, const int* in_sizes, int n_in,
                              void* d_out, int out_size, void* d_ws, size_t ws_size,
                              hipStream_t stream) {
  const float* inp = (const float*)d_in[0];
  const float* wp  = (const float*)d_in[1];
  // d_in[2] (b) cancels in LSE - sim_self.
  float* out = (float*)d_out;

  unsigned char* bsw = (unsigned char*)d_ws;            // 256 KB fp8 B-frags
  float* c_raw = (float*)((char*)d_ws + 256 * 1024);    // 1 MB
  float* ccv   = c_raw + (size_t)N_SPK * D_DIM;         // 4 KB

  ge2e_prep<<<N_SPK / 4, 256, 0, stream>>>(inp, (unsigned int*)bsw, c_raw, ccv,
                                           out);
  ge2e_main<<<(N_SPK * M_UTT) / 32, 256, 0, stream>>>(inp, wp, bsw, c_raw, ccv,
                                                      out);
}